// Round 10
// baseline (494.894 us; speedup 1.0000x reference)
//
#include <hip/hip_runtime.h>

#define NTOK 512
#define CS 384
#define CZ 128
#define CH 16
#define HN 12
#define PQ 4
#define PV 8
#define FEAT_DIM 2112   // HN * 176
#define HSEG 176        // 16 + 24 + 8 + 128

// ---------------------------------------------------------------------------
// K1: all projections as a tiled GEMM: [512 x 384] @ [384 x 1152(concat)]
// (round-8 version: b128 srow broadcasts)
// ---------------------------------------------------------------------------
__global__ __launch_bounds__(256) void k_proj(
    const float* __restrict__ s,
    const float* __restrict__ Wq,  const float* __restrict__ bq,
    const float* __restrict__ Wk,  const float* __restrict__ bk,
    const float* __restrict__ Wv,  const float* __restrict__ bv,
    const float* __restrict__ Wqp, const float* __restrict__ bqp,
    const float* __restrict__ Wkp, const float* __restrict__ bkp,
    const float* __restrict__ Wvp, const float* __restrict__ bvp,
    float* __restrict__ qs, float* __restrict__ ksT, float* __restrict__ vs,
    float* __restrict__ raw_g)
{
    __shared__ float s_l[16 * CS];   // 24 KB
    __shared__ float Ws[16][64];     // 4 KB
    const int t  = threadIdx.x;
    const int n0 = blockIdx.x * 16;

    const float4* sg  = (const float4*)(s + (size_t)n0 * CS);
    float4*       sl4 = (float4*)s_l;
#pragma unroll
    for (int j = 0; j < 6; ++j) sl4[j * 256 + t] = sg[j * 256 + t];

    const int col = blockIdx.y * 64 + (t & 63);
    const int tq  = t >> 6;           // wave id -> token quad (wave-uniform)
    const float* bv_;
    int lc;
    if (col < 192)      { bv_ = bq;  lc = col;       }
    else if (col < 384) { bv_ = bk;  lc = col - 192; }
    else if (col < 576) { bv_ = bv;  lc = col - 384; }
    else if (col < 720) { bv_ = bqp; lc = col - 576; }
    else if (col < 864) { bv_ = bkp; lc = col - 720; }
    else                { bv_ = bvp; lc = col - 864; }

    const int kk_s = t >> 4, cq = t & 15;
    const int gcol = blockIdx.y * 64 + cq * 4;
    const float* Wsrc; int lcs, ncs;
    if (gcol < 192)      { Wsrc = Wq;  lcs = gcol;       ncs = 192; }
    else if (gcol < 384) { Wsrc = Wk;  lcs = gcol - 192; ncs = 192; }
    else if (gcol < 576) { Wsrc = Wv;  lcs = gcol - 384; ncs = 192; }
    else if (gcol < 720) { Wsrc = Wqp; lcs = gcol - 576; ncs = 144; }
    else if (gcol < 864) { Wsrc = Wkp; lcs = gcol - 720; ncs = 144; }
    else                 { Wsrc = Wvp; lcs = gcol - 864; ncs = 288; }

    float a0, a1, a2, a3;
    a0 = a1 = a2 = a3 = bv_[lc];
    __syncthreads();   // s_l ready

    for (int ks = 0; ks < CS; ks += 16) {
        float4 w4 = *(const float4*)&Wsrc[(size_t)(ks + kk_s) * ncs + lcs];
        __syncthreads();   // previous step's Ws reads done
        *(float4*)&Ws[kk_s][cq * 4] = w4;
        __syncthreads();
        const float* srow = s_l + tq * 4 * CS + ks;
#pragma unroll
        for (int k4 = 0; k4 < 4; ++k4) {
            float4 s0 = *(const float4*)&srow[k4 * 4];
            float4 s1 = *(const float4*)&srow[CS + k4 * 4];
            float4 s2 = *(const float4*)&srow[2 * CS + k4 * 4];
            float4 s3 = *(const float4*)&srow[3 * CS + k4 * 4];
            float w0 = Ws[k4 * 4 + 0][t & 63];
            float w1 = Ws[k4 * 4 + 1][t & 63];
            float w2 = Ws[k4 * 4 + 2][t & 63];
            float w3 = Ws[k4 * 4 + 3][t & 63];
            a0 += s0.x * w0 + s0.y * w1 + s0.z * w2 + s0.w * w3;
            a1 += s1.x * w0 + s1.y * w1 + s1.z * w2 + s1.w * w3;
            a2 += s2.x * w0 + s2.y * w1 + s2.z * w2 + s2.w * w3;
            a3 += s3.x * w0 + s3.y * w1 + s3.z * w2 + s3.w * w3;
        }
    }

    const int n = n0 + tq * 4;
    if (col < 192) {
        qs[(size_t)(n + 0) * 192 + lc] = a0;
        qs[(size_t)(n + 1) * 192 + lc] = a1;
        qs[(size_t)(n + 2) * 192 + lc] = a2;
        qs[(size_t)(n + 3) * 192 + lc] = a3;
    } else if (col < 384) {
        float* p = ksT + (size_t)lc * NTOK + n;   // transposed
        p[0] = a0; p[1] = a1; p[2] = a2; p[3] = a3;
    } else if (col < 576) {
        vs[(size_t)(n + 0) * 192 + lc] = a0;
        vs[(size_t)(n + 1) * 192 + lc] = a1;
        vs[(size_t)(n + 2) * 192 + lc] = a2;
        vs[(size_t)(n + 3) * 192 + lc] = a3;
    } else {
        const int pc = col - 576;   // qp[0:144) kp[144:288) vp[288:576)
        raw_g[(size_t)(n + 0) * 576 + pc] = a0;
        raw_g[(size_t)(n + 1) * 576 + pc] = a1;
        raw_g[(size_t)(n + 2) * 576 + pc] = a2;
        raw_g[(size_t)(n + 3) * 576 + pc] = a3;
    }
}

// ---------------------------------------------------------------------------
// K1b: apply frame (local -> global). (round-8 original, wbTg removed)
// ---------------------------------------------------------------------------
__global__ __launch_bounds__(256) void k_frame(
    const float* __restrict__ raw_g,
    const float* __restrict__ trans,
    const float* __restrict__ rot,
    float* __restrict__ qg, float* __restrict__ kgT, float* __restrict__ vg,
    float* __restrict__ transT)
{
    const int e = blockIdx.x * 256 + threadIdx.x;
    if (e < 512 * 576) {
        const int n = e / 576, loc = e % 576;
        const int i = loc % 3, base = loc - i;
        const float* rp = raw_g + (size_t)n * 576 + base;
        float x0 = rp[0], x1 = rp[1], x2 = rp[2];
        const float* R = rot + (size_t)n * 9 + i * 3;
        float v = trans[(size_t)n * 3 + i] + R[0] * x0 + R[1] * x1 + R[2] * x2;
        if (loc < 144)      qg[(size_t)n * 144 + loc] = v;
        else if (loc < 288) kgT[(size_t)(loc - 144) * NTOK + n] = v;   // transposed
        else                vg[(size_t)n * 288 + loc - 288] = v;
    } else {
        const int idx = e - 512 * 576;
        if (idx < 3 * NTOK) {
            const int m = idx / 3, i = idx % 3;
            transT[(size_t)i * NTOK + m] = trans[(size_t)m * 3 + i];
        }
    }
}

// ---------------------------------------------------------------------------
// K2: pair bias = z @ Wb + bb, SPLIT OUT of k_mid (round-10 restructure).
// v5's exact bias loop at 8x the parallelism: grid 4096 = (n, m-chunk of 64),
// 40 KB LDS -> 4 blocks/CU. HBM-bound (z read once, 134 MB). Writes
// bias[n][h][m] into the ATTN buffer; k_mid reads it then overwrites
// in place (same block, read-before-write).
// ---------------------------------------------------------------------------
__global__ __launch_bounds__(256) void k_bias(
    const float* __restrict__ z,
    const float* __restrict__ Wb,
    const float* __restrict__ bbv,
    float* __restrict__ bias)
{
    __shared__ __align__(16) float zl[64 * 132];     // 33 KB row-major pad 132
    __shared__ __align__(16) float wbT[HN * CZ];     // 6 KB [h][c]
    const int t = threadIdx.x;
    const int n = blockIdx.x >> 3, mc = blockIdx.x & 7;

    for (int i = t; i < CZ * HN; i += 256) {
        const int h = i >> 7, c = i & 127;
        wbT[h * CZ + c] = Wb[(size_t)c * HN + h];    // transpose on load
    }
    {
        const float4* zg = (const float4*)(z + ((size_t)n * NTOK + mc * 64) * CZ);
#pragma unroll
        for (int j = 0; j < 8; ++j) {
            float4 v = zg[j * 256 + t];
            const int f = j * 256 + t;
            const int row = f >> 5, c4 = (f & 31) * 4;
            *(float4*)&zl[row * 132 + c4] = v;
        }
    }
    __syncthreads();

    const int ml = t & 63, hg = t >> 6, h0 = hg * 3;
    float b0 = bbv[h0], b1 = bbv[h0 + 1], b2 = bbv[h0 + 2];
    const float* w0 = wbT + (h0 + 0) * CZ;
    const float* w1 = wbT + (h0 + 1) * CZ;
    const float* w2 = wbT + (h0 + 2) * CZ;
    const float* zrow = zl + ml * 132;
#pragma unroll 4
    for (int cq = 0; cq < CZ; cq += 4) {
        float4 zv = *(const float4*)&zrow[cq];
        float4 v0 = *(const float4*)&w0[cq];
        float4 v1 = *(const float4*)&w1[cq];
        float4 v2 = *(const float4*)&w2[cq];
        b0 += zv.x * v0.x + zv.y * v0.y + zv.z * v0.z + zv.w * v0.w;
        b1 += zv.x * v1.x + zv.y * v1.y + zv.z * v1.z + zv.w * v1.w;
        b2 += zv.x * v2.x + zv.y * v2.y + zv.z * v2.z + zv.w * v2.w;
    }
    const int mg = mc * 64 + ml;
    bias[((size_t)n * HN + h0 + 0) * NTOK + mg] = b0;
    bias[((size_t)n * HN + h0 + 1) * NTOK + mg] = b1;
    bias[((size_t)n * HN + h0 + 2) * NTOK + mg] = b2;
}

// ---------------------------------------------------------------------------
// K_mid v8 "lite": v5 minus z-staging minus bias loop (bias precomputed by
// k_bias into the attn buffer; read then overwritten in place).
// No zl -> ZERO barriers in pass 1 (softmax reads only own-wave lgT cols);
// LDS 35 KB -> 4 blocks/CU (2x occupancy for the latency-bound K-side loads).
// Pass 2 unchanged; z reads are L3-warm from k_bias.
// ---------------------------------------------------------------------------
__global__ __launch_bounds__(256, 4) void k_mid(
    const float* __restrict__ z,
    const float* __restrict__ qs, const float* __restrict__ ksT,
    const float* __restrict__ qg, const float* __restrict__ kgT,
    const float* __restrict__ trans, const float* __restrict__ transT,
    const float* __restrict__ emb, const float* __restrict__ slog,
    const float* __restrict__ hw,
    float* __restrict__ attn, float* __restrict__ feats)
{
    __shared__ __align__(16) float lgT[NTOK * HN];   // 24 KB, [m][h]
    __shared__ __align__(16) float out_l[HN * CZ];   // 6 KB merge scratch
    __shared__ float embl[64 * HN];                  // 3 KB [bin][h]
    __shared__ float ql[192];
    __shared__ float qgl[144];
    __shared__ float tl[3];
    __shared__ float phl[36];                        // [s][h]
    __shared__ float hwl[HN];

    const int n = blockIdx.x, t = threadIdx.x;
    const int ml = t & 63, hg = t >> 6, h0 = hg * 3;

    // --- one-time staging ---
    for (int i = t; i < 64 * HN; i += 256) embl[i] = emb[i];
    if (t < 192) ql[t] = qs[(size_t)n * 192 + t];
    if (t < 144) qgl[t] = qg[(size_t)n * 144 + t];
    if (t < 3)   tl[t] = trans[(size_t)n * 3 + t];
    if (t < HN)  hwl[t] = hw[t];
    if (t >= 64 && t < 64 + HN) {
        const int h = t - 64;
        float s0 = slog[h], s1 = slog[HN + h], s2 = slog[2 * HN + h];
        float mx = fmaxf(s0, fmaxf(s1, s2));
        float e0 = expf(s0 - mx), e1 = expf(s1 - mx), e2 = expf(s2 - mx);
        float inv = 1.f / (e0 + e1 + e2);
        phl[h] = e0 * inv; phl[12 + h] = e1 * inv; phl[24 + h] = e2 * inv;
    }
    __syncthreads();   // staging visible

    const float* brow = attn + ((size_t)n * HN + h0) * NTOK;   // bias in

    // pass 1: logits, no barriers (each wave owns its 3 lgT columns)
    for (int mc = 0; mc < 8; ++mc) {
        const int mg = mc * 64 + ml;
        float b0 = brow[mg];
        float b1 = brow[NTOK + mg];
        float b2 = brow[2 * NTOK + mg];
        // distance terms (head-independent)
        float dx = tl[0] - transT[mg];
        float dy = tl[1] - transT[NTOK + mg];
        float dz = tl[2] - transT[2 * NTOK + mg];
        float dist = sqrtf(dx * dx + dy * dy + dz * dz);
        int bin = min(63, max(0, (int)ceilf(dist * 2.f) - 1));
        const float in5  = (dist <= 5.f) ? 1.f : 0.f;
        const float in15 = (dist > 5.f && dist <= 15.f) ? 1.f : 0.f;

        float acc[3] = {b0, b1, b2};
#pragma unroll
        for (int k = 0; k < 3; ++k) {
            const int h = h0 + k;
            float sc = 0.f;
            const float* kk = ksT + (size_t)h * CH * NTOK + mg;
            const float* qq = ql + h * CH;
#pragma unroll
            for (int c = 0; c < CH; ++c) sc += qq[c] * kk[(size_t)c * NTOK];
            float sd = 0.f;
            const float* kg = kgT + (size_t)h * 12 * NTOK + mg;
            const float* qp = qgl + h * 12;
#pragma unroll
            for (int i = 0; i < 12; ++i) {
                float d = qp[i] - kg[(size_t)i * NTOK];
                sd += d * d;
            }
            acc[k] += sc * 0.25f - 0.5f * sd * hwl[h]
                    + embl[bin * HN + h]
                    + phl[24 + h] + in5 * phl[h] + in15 * phl[12 + h];
        }
        lgT[mg * HN + h0 + 0] = acc[0];
        lgT[mg * HN + h0 + 1] = acc[1];
        lgT[mg * HN + h0 + 2] = acc[2];
    }

    // per-wave softmax: wave hg owns heads h0..h0+2 (own lgT columns; the
    // values were written by this same wave -> no barrier needed)
    const int lane = t & 63;
#pragma unroll
    for (int hh = 0; hh < 3; ++hh) {
        const int h = h0 + hh;
        float v[8];
        float mx = -1e30f;
#pragma unroll
        for (int i = 0; i < 8; ++i) {
            v[i] = lgT[(lane + 64 * i) * HN + h];
            mx = fmaxf(mx, v[i]);
        }
#pragma unroll
        for (int off = 32; off; off >>= 1) mx = fmaxf(mx, __shfl_xor(mx, off));
        float sm = 0.f;
#pragma unroll
        for (int i = 0; i < 8; ++i) { v[i] = expf(v[i] - mx); sm += v[i]; }
#pragma unroll
        for (int off = 32; off; off >>= 1) sm += __shfl_xor(sm, off);
        const float inv = 1.f / sm;
        float* arow = attn + ((size_t)n * HN + h) * NTOK;
#pragma unroll
        for (int i = 0; i < 8; ++i) {
            float a = v[i] * inv;
            lgT[(lane + 64 * i) * HN + h] = a;   // in-place for pass 2
            arow[lane + 64 * i] = a;             // global (overwrites bias)
        }
    }
    __syncthreads();   // all heads' attn visible in lgT

    // pass 2: pair_feat = attn @ z[n]; attn via 3 broadcast b128/m, z L3-warm
    const int slab = hg;                // m-quarter
    const int c2 = ml * 2;
    float pacc[HN][2];
#pragma unroll
    for (int h = 0; h < HN; ++h) { pacc[h][0] = 0.f; pacc[h][1] = 0.f; }
    const float* zp = z + (size_t)n * NTOK * CZ + (size_t)slab * 128 * CZ + c2;
    const float* lp = lgT + slab * 128 * HN;
#pragma unroll 4
    for (int m = 0; m < 128; ++m) {
        float2 zv = *(const float2*)(zp + (size_t)m * CZ);
        float4 a0 = *(const float4*)&lp[m * HN + 0];
        float4 a1 = *(const float4*)&lp[m * HN + 4];
        float4 a2 = *(const float4*)&lp[m * HN + 8];
        pacc[0][0]  += a0.x * zv.x;  pacc[0][1]  += a0.x * zv.y;
        pacc[1][0]  += a0.y * zv.x;  pacc[1][1]  += a0.y * zv.y;
        pacc[2][0]  += a0.z * zv.x;  pacc[2][1]  += a0.z * zv.y;
        pacc[3][0]  += a0.w * zv.x;  pacc[3][1]  += a0.w * zv.y;
        pacc[4][0]  += a1.x * zv.x;  pacc[4][1]  += a1.x * zv.y;
        pacc[5][0]  += a1.y * zv.x;  pacc[5][1]  += a1.y * zv.y;
        pacc[6][0]  += a1.z * zv.x;  pacc[6][1]  += a1.z * zv.y;
        pacc[7][0]  += a1.w * zv.x;  pacc[7][1]  += a1.w * zv.y;
        pacc[8][0]  += a2.x * zv.x;  pacc[8][1]  += a2.x * zv.y;
        pacc[9][0]  += a2.y * zv.x;  pacc[9][1]  += a2.y * zv.y;
        pacc[10][0] += a2.z * zv.x;  pacc[10][1] += a2.z * zv.y;
        pacc[11][0] += a2.w * zv.x;  pacc[11][1] += a2.w * zv.y;
    }
    // merge 4 slabs
    for (int s = 0; s < 4; ++s) {
        __syncthreads();
        if (slab == s) {
#pragma unroll
            for (int h = 0; h < HN; ++h) {
                float* p = &out_l[h * CZ + c2];
                if (s == 0) { p[0] = pacc[h][0]; p[1] = pacc[h][1]; }
                else        { p[0] += pacc[h][0]; p[1] += pacc[h][1]; }
            }
        }
    }
    __syncthreads();
    for (int i = t; i < HN * CZ; i += 256) {
        const int h = i >> 7, c = i & 127;
        feats[(size_t)n * FEAT_DIM + h * HSEG + 48 + c] = out_l[i];
    }
}

// ---------------------------------------------------------------------------
// K4: out_scalar + out_pts_g tiled GEMM per (n-tile 32, h); epilogue fused.
// (unchanged)
// ---------------------------------------------------------------------------
__global__ __launch_bounds__(256) void k_outmm(
    const float* __restrict__ attn,
    const float* __restrict__ vs, const float* __restrict__ vg,
    const float* __restrict__ trans,
    const float* __restrict__ rot,
    float* __restrict__ feats)
{
    __shared__ float As_t[64][33];     // [m][n], +1 pad (8.4 KB)
    __shared__ float Vs[64][40];       // [m][j]  (10.2 KB)
    __shared__ float out_l[32 * 40];   // merged sums (5 KB)
    __shared__ float Rl[32][9];
    __shared__ float tl[32][3];
    const int t   = threadIdx.x;
    const int gn0 = blockIdx.x * 32;
    const int h   = blockIdx.y;

    const int slab  = t >> 6;          // wave id -> m quarter
    const int w     = t & 63;
    const int n0l   = (w >> 3) * 4;    // 8 n-groups of 4
    const int j0    = (w & 7) * 5;     // 8 j-groups of 5

    float acc[4][5];
#pragma unroll
    for (int i = 0; i < 4; ++i)
#pragma unroll
        for (int k = 0; k < 5; ++k) acc[i][k] = 0.f;

    for (int step = 0; step < 8; ++step) {
        const int mb = step * 64;
        __syncthreads();
#pragma unroll
        for (int jj = 0; jj < 2; ++jj) {
            const int f = t + jj * 256;
            const int n_loc = f >> 4, c4 = f & 15;
            float4 a = *(const float4*)&attn[(((size_t)(gn0 + n_loc)) * HN + h) * NTOK + mb + c4 * 4];
            As_t[c4 * 4 + 0][n_loc] = a.x;
            As_t[c4 * 4 + 1][n_loc] = a.y;
            As_t[c4 * 4 + 2][n_loc] = a.z;
            As_t[c4 * 4 + 3][n_loc] = a.w;
        }
#pragma unroll
        for (int jj = 0; jj < 10; ++jj) {
            const int f = t + jj * 256;
            const int m_loc = f / 40, jv = f % 40;
            float v;
            if (jv < 16) v = vs[(size_t)(mb + m_loc) * 192 + h * 16 + jv];
            else         v = vg[(size_t)(mb + m_loc) * 288 + h * 24 + (jv - 16)];
            Vs[m_loc][jv] = v;
        }
        __syncthreads();
#pragma unroll
        for (int mi = 0; mi < 16; ++mi) {
            const int m = slab * 16 + mi;
            float4 a = *(const float4*)&As_t[m][n0l];
            float vv[5];
#pragma unroll
            for (int k = 0; k < 5; ++k) vv[k] = Vs[m][j0 + k];
            const float av[4] = {a.x, a.y, a.z, a.w};
#pragma unroll
            for (int i = 0; i < 4; ++i)
#pragma unroll
                for (int k = 0; k < 5; ++k)
                    acc[i][k] += av[i] * vv[k];
        }
    }

    for (int s = 0; s < 4; ++s) {
        __syncthreads();
        if (slab == s) {
#pragma unroll
            for (int i = 0; i < 4; ++i)
#pragma unroll
                for (int k = 0; k < 5; ++k) {
                    float* p = &out_l[(n0l + i) * 40 + j0 + k];
                    if (s == 0) *p = acc[i][k];
                    else        *p += acc[i][k];
                }
        }
    }
    for (int i = t; i < 32 * 12; i += 256) {
        const int n_loc = i / 12, r = i % 12;
        if (r < 9) Rl[n_loc][r] = rot[(size_t)(gn0 + n_loc) * 9 + r];
        else       tl[n_loc][r - 9] = trans[(size_t)(gn0 + n_loc) * 3 + (r - 9)];
    }
    __syncthreads();

    for (int f = t; f < 32 * 48; f += 256) {
        const int n_loc = f / 48, j = f % 48;
        const float* sh = &out_l[n_loc * 40];
        float* fp = feats + (size_t)(gn0 + n_loc) * FEAT_DIM + h * HSEG;
        const float* R = Rl[n_loc];
        const float* tv = tl[n_loc];
        if (j < 16) {
            fp[j] = sh[j];
        } else if (j < 40) {
            const int jj = j - 16, p = jj / 3, i = jj % 3;
            float val = 0.f;
#pragma unroll
            for (int q = 0; q < 3; ++q) val += R[q * 3 + i] * (sh[16 + p * 3 + q] - tv[q]);
            fp[16 + jj] = val;
        } else {
            const int p = j - 40;
            float s2 = 0.f;
#pragma unroll
            for (int i = 0; i < 3; ++i) {
                float val = 0.f;
#pragma unroll
                for (int q = 0; q < 3; ++q) val += R[q * 3 + i] * (sh[16 + p * 3 + q] - tv[q]);
                s2 += val * val;
            }
            fp[40 + p] = sqrtf(s2);
        }
    }
}

// ---------------------------------------------------------------------------
// K6: out = feats @ Wout + bout  (unchanged)
// ---------------------------------------------------------------------------
#define KT 16
__global__ __launch_bounds__(256) void k_outproj(
    const float* __restrict__ feats,
    const float* __restrict__ Wout,
    const float* __restrict__ bout,
    float* __restrict__ out)
{
    __shared__ float As[KT][64];   // As[k][row]
    __shared__ float Bs[KT][64];   // Bs[k][col]
    const int t  = threadIdx.x;
    const int n0 = blockIdx.x * 64;
    const int j0 = blockIdx.y * 64;
    const int k0 = blockIdx.z * HSEG;

    const int arow = t >> 2, akq = (t & 3) * 4;
    const int bkk  = t >> 4, bjq = (t & 15) * 4;
    const int tr   = t >> 4, tc  = t & 15;

    float acc[4][4] = {{0.f}};
    for (int s = 0; s < 11; ++s) {
        const int ks = k0 + s * KT;
        float4 a4 = *(const float4*)&feats[(size_t)(n0 + arow) * FEAT_DIM + ks + akq];
        float4 b4 = *(const float4*)&Wout[(size_t)(ks + bkk) * 384 + j0 + bjq];
        __syncthreads();
        As[akq + 0][arow] = a4.x;
        As[akq + 1][arow] = a4.y;
        As[akq + 2][arow] = a4.z;
        As[akq + 3][arow] = a4.w;
        *(float4*)&Bs[bkk][bjq] = b4;
        __syncthreads();
#pragma unroll
        for (int kk = 0; kk < KT; ++kk) {
            float4 av = *(const float4*)&As[kk][tr * 4];
            float4 bv = *(const float4*)&Bs[kk][tc * 4];
            acc[0][0] += av.x * bv.x; acc[0][1] += av.x * bv.y;
            acc[0][2] += av.x * bv.z; acc[0][3] += av.x * bv.w;
            acc[1][0] += av.y * bv.x; acc[1][1] += av.y * bv.y;
            acc[1][2] += av.y * bv.z; acc[1][3] += av.y * bv.w;
            acc[2][0] += av.z * bv.x; acc[2][1] += av.z * bv.y;
            acc[2][2] += av.z * bv.z; acc[2][3] += av.z * bv.w;
            acc[3][0] += av.w * bv.x; acc[3][1] += av.w * bv.y;
            acc[3][2] += av.w * bv.z; acc[3][3] += av.w * bv.w;
        }
    }

    const bool addb = (blockIdx.z == 0);
#pragma unroll
    for (int i = 0; i < 4; ++i) {
        const int row = n0 + tr * 4 + i;
#pragma unroll
        for (int jj = 0; jj < 4; ++jj) {
            const int col = j0 + tc * 4 + jj;
            float v = acc[i][jj];
            if (addb) v += bout[col];
            atomicAdd(&out[(size_t)row * 384 + col], v);
        }
    }
}

// ---------------------------------------------------------------------------
extern "C" void kernel_launch(void* const* d_in, const int* in_sizes, int n_in,
                              void* d_out, int out_size, void* d_ws, size_t ws_size,
                              hipStream_t stream) {
    const float* s     = (const float*)d_in[0];
    const float* z     = (const float*)d_in[1];
    const float* trans = (const float*)d_in[2];
    const float* rot   = (const float*)d_in[3];
    const float* Wq    = (const float*)d_in[4];
    const float* bq    = (const float*)d_in[5];
    const float* Wk    = (const float*)d_in[6];
    const float* bk    = (const float*)d_in[7];
    const float* Wv    = (const float*)d_in[8];
    const float* bv    = (const float*)d_in[9];
    const float* Wqp   = (const float*)d_in[10];
    const float* bqp   = (const float*)d_in[11];
    const float* Wkp   = (const float*)d_in[12];
    const float* bkp   = (const float*)d_in[13];
    const float* Wvp   = (const float*)d_in[14];
    const float* bvp   = (const float*)d_in[15];
    const float* Wb    = (const float*)d_in[16];
    const float* bb    = (const float*)d_in[17];
    const float* emb   = (const float*)d_in[18];
    const float* slog  = (const float*)d_in[19];
    const float* hw    = (const float*)d_in[20];
    const float* Wout  = (const float*)d_in[21];
    const float* bout  = (const float*)d_in[22];

    float* W = (float*)d_ws;
    float* qs     = W;                    // 512*192
    float* ksT    = qs + 98304;           // 192*512 (transposed)
    float* vs     = ksT + 98304;          // 512*192
    float* qg     = vs + 98304;           // 512*144
    float* kgT    = qg + 73728;           // 144*512 (transposed)
    float* vg     = kgT + 73728;          // 512*288
    float* transT = vg + 147456;          // 3*512
    float* attn   = transT + 1536;        // 512*12*512 (bias in, attn out)
    float* feats  = attn + 3145728;       // 512*2112
    float* raw_g  = feats + 1081344;      // 512*576
    // total: ~5.11M floats = 20.5 MB

    k_bias<<<4096, 256, 0, stream>>>(z, Wb, bb, attn);
    k_proj<<<dim3(32, 18), 256, 0, stream>>>(s, Wq, bq, Wk, bk, Wv, bv,
                                             Wqp, bqp, Wkp, bkp, Wvp, bvp,
                                             qs, ksT, vs, raw_g);
    k_frame<<<1158, 256, 0, stream>>>(raw_g, trans, rot, qg, kgT, vg, transT);
    k_mid<<<512, 256, 0, stream>>>(z, qs, ksT, qg, kgT, trans, transT,
                                   emb, slog, hw, attn, feats);
    k_outmm<<<dim3(16, 12), 256, 0, stream>>>(attn, vs, vg, trans, rot, feats);
    hipMemsetAsync(d_out, 0, (size_t)NTOK * 384 * sizeof(float), stream);
    k_outproj<<<dim3(8, 6, 12), 256, 0, stream>>>(feats, Wout, bout, (float*)d_out);
}

// Round 11
// 382.636 us; speedup vs baseline: 1.2934x; 1.2934x over previous
//
#include <hip/hip_runtime.h>

#define NTOK 512
#define CS 384
#define CZ 128
#define CH 16
#define HN 12
#define PQ 4
#define PV 8
#define FEAT_DIM 2112   // HN * 176
#define HSEG 176        // 16 + 24 + 8 + 128

// ---------------------------------------------------------------------------
// K1: all projections as a tiled GEMM: [512 x 384] @ [384 x 1152(concat)]
// (round-8 version: b128 srow broadcasts)
// ---------------------------------------------------------------------------
__global__ __launch_bounds__(256) void k_proj(
    const float* __restrict__ s,
    const float* __restrict__ Wq,  const float* __restrict__ bq,
    const float* __restrict__ Wk,  const float* __restrict__ bk,
    const float* __restrict__ Wv,  const float* __restrict__ bv,
    const float* __restrict__ Wqp, const float* __restrict__ bqp,
    const float* __restrict__ Wkp, const float* __restrict__ bkp,
    const float* __restrict__ Wvp, const float* __restrict__ bvp,
    float* __restrict__ qs, float* __restrict__ ksT, float* __restrict__ vs,
    float* __restrict__ raw_g)
{
    __shared__ float s_l[16 * CS];   // 24 KB
    __shared__ float Ws[16][64];     // 4 KB
    const int t  = threadIdx.x;
    const int n0 = blockIdx.x * 16;

    const float4* sg  = (const float4*)(s + (size_t)n0 * CS);
    float4*       sl4 = (float4*)s_l;
#pragma unroll
    for (int j = 0; j < 6; ++j) sl4[j * 256 + t] = sg[j * 256 + t];

    const int col = blockIdx.y * 64 + (t & 63);
    const int tq  = t >> 6;           // wave id -> token quad (wave-uniform)
    const float* bv_;
    int lc;
    if (col < 192)      { bv_ = bq;  lc = col;       }
    else if (col < 384) { bv_ = bk;  lc = col - 192; }
    else if (col < 576) { bv_ = bv;  lc = col - 384; }
    else if (col < 720) { bv_ = bqp; lc = col - 576; }
    else if (col < 864) { bv_ = bkp; lc = col - 720; }
    else                { bv_ = bvp; lc = col - 864; }

    const int kk_s = t >> 4, cq = t & 15;
    const int gcol = blockIdx.y * 64 + cq * 4;
    const float* Wsrc; int lcs, ncs;
    if (gcol < 192)      { Wsrc = Wq;  lcs = gcol;       ncs = 192; }
    else if (gcol < 384) { Wsrc = Wk;  lcs = gcol - 192; ncs = 192; }
    else if (gcol < 576) { Wsrc = Wv;  lcs = gcol - 384; ncs = 192; }
    else if (gcol < 720) { Wsrc = Wqp; lcs = gcol - 576; ncs = 144; }
    else if (gcol < 864) { Wsrc = Wkp; lcs = gcol - 720; ncs = 144; }
    else                 { Wsrc = Wvp; lcs = gcol - 864; ncs = 288; }

    float a0, a1, a2, a3;
    a0 = a1 = a2 = a3 = bv_[lc];
    __syncthreads();   // s_l ready

    for (int ks = 0; ks < CS; ks += 16) {
        float4 w4 = *(const float4*)&Wsrc[(size_t)(ks + kk_s) * ncs + lcs];
        __syncthreads();   // previous step's Ws reads done
        *(float4*)&Ws[kk_s][cq * 4] = w4;
        __syncthreads();
        const float* srow = s_l + tq * 4 * CS + ks;
#pragma unroll
        for (int k4 = 0; k4 < 4; ++k4) {
            float4 s0 = *(const float4*)&srow[k4 * 4];
            float4 s1 = *(const float4*)&srow[CS + k4 * 4];
            float4 s2 = *(const float4*)&srow[2 * CS + k4 * 4];
            float4 s3 = *(const float4*)&srow[3 * CS + k4 * 4];
            float w0 = Ws[k4 * 4 + 0][t & 63];
            float w1 = Ws[k4 * 4 + 1][t & 63];
            float w2 = Ws[k4 * 4 + 2][t & 63];
            float w3 = Ws[k4 * 4 + 3][t & 63];
            a0 += s0.x * w0 + s0.y * w1 + s0.z * w2 + s0.w * w3;
            a1 += s1.x * w0 + s1.y * w1 + s1.z * w2 + s1.w * w3;
            a2 += s2.x * w0 + s2.y * w1 + s2.z * w2 + s2.w * w3;
            a3 += s3.x * w0 + s3.y * w1 + s3.z * w2 + s3.w * w3;
        }
    }

    const int n = n0 + tq * 4;
    if (col < 192) {
        qs[(size_t)(n + 0) * 192 + lc] = a0;
        qs[(size_t)(n + 1) * 192 + lc] = a1;
        qs[(size_t)(n + 2) * 192 + lc] = a2;
        qs[(size_t)(n + 3) * 192 + lc] = a3;
    } else if (col < 384) {
        float* p = ksT + (size_t)lc * NTOK + n;   // transposed
        p[0] = a0; p[1] = a1; p[2] = a2; p[3] = a3;
    } else if (col < 576) {
        vs[(size_t)(n + 0) * 192 + lc] = a0;
        vs[(size_t)(n + 1) * 192 + lc] = a1;
        vs[(size_t)(n + 2) * 192 + lc] = a2;
        vs[(size_t)(n + 3) * 192 + lc] = a3;
    } else {
        const int pc = col - 576;   // qp[0:144) kp[144:288) vp[288:576)
        raw_g[(size_t)(n + 0) * 576 + pc] = a0;
        raw_g[(size_t)(n + 1) * 576 + pc] = a1;
        raw_g[(size_t)(n + 2) * 576 + pc] = a2;
        raw_g[(size_t)(n + 3) * 576 + pc] = a3;
    }
}

// ---------------------------------------------------------------------------
// K1b: apply frame (local -> global). (unchanged)
// ---------------------------------------------------------------------------
__global__ __launch_bounds__(256) void k_frame(
    const float* __restrict__ raw_g,
    const float* __restrict__ trans,
    const float* __restrict__ rot,
    float* __restrict__ qg, float* __restrict__ kgT, float* __restrict__ vg,
    float* __restrict__ transT)
{
    const int e = blockIdx.x * 256 + threadIdx.x;
    if (e < 512 * 576) {
        const int n = e / 576, loc = e % 576;
        const int i = loc % 3, base = loc - i;
        const float* rp = raw_g + (size_t)n * 576 + base;
        float x0 = rp[0], x1 = rp[1], x2 = rp[2];
        const float* R = rot + (size_t)n * 9 + i * 3;
        float v = trans[(size_t)n * 3 + i] + R[0] * x0 + R[1] * x1 + R[2] * x2;
        if (loc < 144)      qg[(size_t)n * 144 + loc] = v;
        else if (loc < 288) kgT[(size_t)(loc - 144) * NTOK + n] = v;   // transposed
        else                vg[(size_t)n * 288 + loc - 288] = v;
    } else {
        const int idx = e - 512 * 576;
        if (idx < 3 * NTOK) {
            const int m = idx / 3, i = idx % 3;
            transT[(size_t)i * NTOK + m] = trans[(size_t)m * 3 + i];
        }
    }
}

// ---------------------------------------------------------------------------
// K_mid v5 (RESTORED: verified 92 us, zero spill, three independent runs).
// Round-10 split post-mortem: grid 512 on 256 CUs = 2 blocks/CU regardless
// of LDS, so the "occupancy doubling" was arithmetic error; and VGPR=64
// allocator squeeze re-spilled (WRITE 105 MB). v5 fusion stands.
// ---------------------------------------------------------------------------
__global__ __launch_bounds__(256, 2) void k_mid(
    const float* __restrict__ z,
    const float* __restrict__ qs, const float* __restrict__ ksT,
    const float* __restrict__ qg, const float* __restrict__ kgT,
    const float* __restrict__ trans, const float* __restrict__ transT,
    const float* __restrict__ Wb, const float* __restrict__ bbv,
    const float* __restrict__ emb, const float* __restrict__ slog,
    const float* __restrict__ hw,
    float* __restrict__ attn, float* __restrict__ feats)
{
    __shared__ __align__(16) float lgT[NTOK * HN];   // 24 KB, [m][h]
    __shared__ __align__(16) float zl[64 * 132];     // 33 KB, row-major pad 132
    __shared__ __align__(16) float wbT[HN * CZ];     // 6 KB, TRANSPOSED [h][c]
    __shared__ float embl[64 * HN];                  // 3 KB [bin][h]
    __shared__ float ql[192];
    __shared__ float qgl[144];
    __shared__ float tl[3];
    __shared__ float phl[36];                        // [s][h]
    __shared__ float hwl[HN];

    const int n = blockIdx.x, t = threadIdx.x;

    // --- one-time staging ---
    for (int i = t; i < CZ * HN; i += 256) {
        const int h = i >> 7, c = i & 127;
        wbT[h * CZ + c] = Wb[(size_t)c * HN + h];    // transpose on load
    }
    for (int i = t; i < 64 * HN; i += 256) embl[i] = emb[i];
    if (t < 192) ql[t] = qs[(size_t)n * 192 + t];
    if (t < 144) qgl[t] = qg[(size_t)n * 144 + t];
    if (t < 3)   tl[t] = trans[(size_t)n * 3 + t];
    if (t < HN)  hwl[t] = hw[t];
    if (t >= 64 && t < 64 + HN) {
        const int h = t - 64;
        float s0 = slog[h], s1 = slog[HN + h], s2 = slog[2 * HN + h];
        float mx = fmaxf(s0, fmaxf(s1, s2));
        float e0 = expf(s0 - mx), e1 = expf(s1 - mx), e2 = expf(s2 - mx);
        float inv = 1.f / (e0 + e1 + e2);
        phl[h] = e0 * inv; phl[12 + h] = e1 * inv; phl[24 + h] = e2 * inv;
    }

    const int ml = t & 63, hg = t >> 6, h0 = hg * 3;
    const float bb0 = bbv[h0], bb1 = bbv[h0 + 1], bb2 = bbv[h0 + 2];

    const float* w0 = wbT + (h0 + 0) * CZ;
    const float* w1 = wbT + (h0 + 1) * CZ;
    const float* w2 = wbT + (h0 + 2) * CZ;

    for (int mc = 0; mc < 8; ++mc) {
        __syncthreads();   // mc=0: one-time staging; mc>0: prev zl reads done
        // stage chunk mc: load -> LDS within the phase (no cross-barrier regs)
        {
            const float4* zg = (const float4*)(z + ((size_t)n * NTOK + mc * 64) * CZ);
#pragma unroll
            for (int j = 0; j < 8; ++j) {
                float4 v = zg[j * 256 + t];
                const int f = j * 256 + t;
                const int row = f >> 5, c4 = (f & 31) * 4;
                *(float4*)&zl[row * 132 + c4] = v;
            }
        }
        __syncthreads();   // zl ready

        const int mg = mc * 64 + ml;
        // pair bias for 3 heads: own-row b128 + broadcast b128 weights
        float b0 = bb0, b1 = bb1, b2 = bb2;
        const float* zrow = zl + ml * 132;
#pragma unroll 4
        for (int cq = 0; cq < CZ; cq += 4) {
            float4 zv = *(const float4*)&zrow[cq];
            float4 v0 = *(const float4*)&w0[cq];
            float4 v1 = *(const float4*)&w1[cq];
            float4 v2 = *(const float4*)&w2[cq];
            b0 += zv.x * v0.x + zv.y * v0.y + zv.z * v0.z + zv.w * v0.w;
            b1 += zv.x * v1.x + zv.y * v1.y + zv.z * v1.z + zv.w * v1.w;
            b2 += zv.x * v2.x + zv.y * v2.y + zv.z * v2.z + zv.w * v2.w;
        }
        // distance terms (head-independent)
        float dx = tl[0] - transT[mg];
        float dy = tl[1] - transT[NTOK + mg];
        float dz = tl[2] - transT[2 * NTOK + mg];
        float dist = sqrtf(dx * dx + dy * dy + dz * dz);
        int bin = min(63, max(0, (int)ceilf(dist * 2.f) - 1));
        const float in5  = (dist <= 5.f) ? 1.f : 0.f;
        const float in15 = (dist > 5.f && dist <= 15.f) ? 1.f : 0.f;

        float acc[3] = {b0, b1, b2};
#pragma unroll
        for (int k = 0; k < 3; ++k) {
            const int h = h0 + k;
            float sc = 0.f;
            const float* kk = ksT + (size_t)h * CH * NTOK + mg;
            const float* qq = ql + h * CH;
#pragma unroll
            for (int c = 0; c < CH; ++c) sc += qq[c] * kk[(size_t)c * NTOK];
            float sd = 0.f;
            const float* kg = kgT + (size_t)h * 12 * NTOK + mg;
            const float* qp = qgl + h * 12;
#pragma unroll
            for (int i = 0; i < 12; ++i) {
                float d = qp[i] - kg[(size_t)i * NTOK];
                sd += d * d;
            }
            acc[k] += sc * 0.25f - 0.5f * sd * hwl[h]
                    + embl[bin * HN + h]
                    + phl[24 + h] + in5 * phl[h] + in15 * phl[12 + h];
        }
        lgT[mg * HN + h0 + 0] = acc[0];
        lgT[mg * HN + h0 + 1] = acc[1];
        lgT[mg * HN + h0 + 2] = acc[2];
    }
    __syncthreads();   // all logits written (also last zl reads done)

    // per-wave softmax: wave hg owns heads h0..h0+2
    const int lane = t & 63;
#pragma unroll
    for (int hh = 0; hh < 3; ++hh) {
        const int h = h0 + hh;
        float v[8];
        float mx = -1e30f;
#pragma unroll
        for (int i = 0; i < 8; ++i) {
            v[i] = lgT[(lane + 64 * i) * HN + h];
            mx = fmaxf(mx, v[i]);
        }
#pragma unroll
        for (int off = 32; off; off >>= 1) mx = fmaxf(mx, __shfl_xor(mx, off));
        float sm = 0.f;
#pragma unroll
        for (int i = 0; i < 8; ++i) { v[i] = expf(v[i] - mx); sm += v[i]; }
#pragma unroll
        for (int off = 32; off; off >>= 1) sm += __shfl_xor(sm, off);
        const float inv = 1.f / sm;
        float* arow = attn + ((size_t)n * HN + h) * NTOK;
#pragma unroll
        for (int i = 0; i < 8; ++i) {
            float a = v[i] * inv;
            lgT[(lane + 64 * i) * HN + h] = a;   // in-place for pass 2
            arow[lane + 64 * i] = a;             // global for k_outmm
        }
    }
    __syncthreads();   // all heads' attn visible in lgT

    // pass 2: pair_feat = attn @ z[n]; attn via 3 broadcast b128/m, z L2-warm
    const int slab = t >> 6;            // m-quarter
    const int c2 = (t & 63) * 2;
    float pacc[HN][2];
#pragma unroll
    for (int h = 0; h < HN; ++h) { pacc[h][0] = 0.f; pacc[h][1] = 0.f; }
    const float* zp = z + (size_t)n * NTOK * CZ + (size_t)slab * 128 * CZ + c2;
    const float* lp = lgT + slab * 128 * HN;
#pragma unroll 4
    for (int m = 0; m < 128; ++m) {
        float2 zv = *(const float2*)(zp + (size_t)m * CZ);
        float4 a0 = *(const float4*)&lp[m * HN + 0];
        float4 a1 = *(const float4*)&lp[m * HN + 4];
        float4 a2 = *(const float4*)&lp[m * HN + 8];
        pacc[0][0]  += a0.x * zv.x;  pacc[0][1]  += a0.x * zv.y;
        pacc[1][0]  += a0.y * zv.x;  pacc[1][1]  += a0.y * zv.y;
        pacc[2][0]  += a0.z * zv.x;  pacc[2][1]  += a0.z * zv.y;
        pacc[3][0]  += a0.w * zv.x;  pacc[3][1]  += a0.w * zv.y;
        pacc[4][0]  += a1.x * zv.x;  pacc[4][1]  += a1.x * zv.y;
        pacc[5][0]  += a1.y * zv.x;  pacc[5][1]  += a1.y * zv.y;
        pacc[6][0]  += a1.z * zv.x;  pacc[6][1]  += a1.z * zv.y;
        pacc[7][0]  += a1.w * zv.x;  pacc[7][1]  += a1.w * zv.y;
        pacc[8][0]  += a2.x * zv.x;  pacc[8][1]  += a2.x * zv.y;
        pacc[9][0]  += a2.y * zv.x;  pacc[9][1]  += a2.y * zv.y;
        pacc[10][0] += a2.z * zv.x;  pacc[10][1] += a2.z * zv.y;
        pacc[11][0] += a2.w * zv.x;  pacc[11][1] += a2.w * zv.y;
    }
    float* out_l = zl;   // reuse scratch (1536 of 8448 floats)
    for (int s = 0; s < 4; ++s) {
        __syncthreads();
        if (slab == s) {
#pragma unroll
            for (int h = 0; h < HN; ++h) {
                float* p = &out_l[h * CZ + c2];
                if (s == 0) { p[0] = pacc[h][0]; p[1] = pacc[h][1]; }
                else        { p[0] += pacc[h][0]; p[1] += pacc[h][1]; }
            }
        }
    }
    __syncthreads();
    for (int i = t; i < HN * CZ; i += 256) {
        const int h = i >> 7, c = i & 127;
        feats[(size_t)n * FEAT_DIM + h * HSEG + 48 + c] = out_l[i];
    }
}

// ---------------------------------------------------------------------------
// K4 v2: out_scalar + out_pts_g GEMM. n-tile 32 -> 8: grid (64,12) = 768
// blocks (3/CU vs 192 blocks = <1/CU). Was latency-bound with 1 wave/SIMD
// and ~22 barriers; same FLOPs, V re-reads 4x (61 MB, L2-resident).
// ---------------------------------------------------------------------------
__global__ __launch_bounds__(256) void k_outmm(
    const float* __restrict__ attn,
    const float* __restrict__ vs, const float* __restrict__ vg,
    const float* __restrict__ trans,
    const float* __restrict__ rot,
    float* __restrict__ feats)
{
    __shared__ float As_t[64][9];      // [m][n], +1 pad (2.3 KB)
    __shared__ float Vs[64][40];       // [m][j]  (10.2 KB)
    __shared__ float out_l[8 * 40];    // merged sums (1.3 KB)
    __shared__ float Rl[8][9];
    __shared__ float tl[8][3];
    const int t   = threadIdx.x;
    const int gn0 = blockIdx.x * 8;
    const int h   = blockIdx.y;

    const int slab = t >> 6;           // wave id -> m quarter
    const int w    = t & 63;
    const int n0l  = w >> 3;           // 8 n rows
    const int j0   = (w & 7) * 5;      // 8 j-groups of 5

    float acc[5] = {0.f, 0.f, 0.f, 0.f, 0.f};

    for (int step = 0; step < 8; ++step) {
        const int mb = step * 64;
        __syncthreads();
        // stage A^T: 8 n x 64 m (one coalesced row per wave per pass)
#pragma unroll
        for (int jj = 0; jj < 2; ++jj) {
            const int f = t + jj * 256;
            const int n_loc = f >> 6, m_loc = f & 63;
            As_t[m_loc][n_loc] =
                attn[(((size_t)(gn0 + n_loc)) * HN + h) * NTOK + mb + m_loc];
        }
        // stage V chunk: 2560 floats
#pragma unroll
        for (int jj = 0; jj < 10; ++jj) {
            const int f = t + jj * 256;
            const int m_loc = f / 40, jv = f % 40;
            float v;
            if (jv < 16) v = vs[(size_t)(mb + m_loc) * 192 + h * 16 + jv];
            else         v = vg[(size_t)(mb + m_loc) * 288 + h * 24 + (jv - 16)];
            Vs[m_loc][jv] = v;
        }
        __syncthreads();
#pragma unroll
        for (int mi = 0; mi < 16; ++mi) {
            const int m = slab * 16 + mi;
            float av = As_t[m][n0l];
            acc[0] += av * Vs[m][j0 + 0];
            acc[1] += av * Vs[m][j0 + 1];
            acc[2] += av * Vs[m][j0 + 2];
            acc[3] += av * Vs[m][j0 + 3];
            acc[4] += av * Vs[m][j0 + 4];
        }
    }

    // merge the 4 m-quarter slabs
    for (int s = 0; s < 4; ++s) {
        __syncthreads();
        if (slab == s) {
            float* p = &out_l[n0l * 40 + j0];
            if (s == 0) {
#pragma unroll
                for (int k = 0; k < 5; ++k) p[k] = acc[k];
            } else {
#pragma unroll
                for (int k = 0; k < 5; ++k) p[k] += acc[k];
            }
        }
    }
    // stage frames
    for (int i = t; i < 8 * 12; i += 256) {
        const int n_loc = i / 12, r = i % 12;
        if (r < 9) Rl[n_loc][r] = rot[(size_t)(gn0 + n_loc) * 9 + r];
        else       tl[n_loc][r - 9] = trans[(size_t)(gn0 + n_loc) * 3 + (r - 9)];
    }
    __syncthreads();

    // epilogue: 8 n x 48 outputs (16 scalar, 24 local pts, 8 norms)
    for (int f = t; f < 8 * 48; f += 256) {
        const int n_loc = f / 48, j = f % 48;
        const float* sh = &out_l[n_loc * 40];
        float* fp = feats + (size_t)(gn0 + n_loc) * FEAT_DIM + h * HSEG;
        const float* R = Rl[n_loc];
        const float* tv = tl[n_loc];
        if (j < 16) {
            fp[j] = sh[j];
        } else if (j < 40) {
            const int jj = j - 16, p = jj / 3, i = jj % 3;
            float val = 0.f;
#pragma unroll
            for (int q = 0; q < 3; ++q) val += R[q * 3 + i] * (sh[16 + p * 3 + q] - tv[q]);
            fp[16 + jj] = val;
        } else {
            const int p = j - 40;
            float s2 = 0.f;
#pragma unroll
            for (int i = 0; i < 3; ++i) {
                float val = 0.f;
#pragma unroll
                for (int q = 0; q < 3; ++q) val += R[q * 3 + i] * (sh[16 + p * 3 + q] - tv[q]);
                s2 += val * val;
            }
            fp[40 + p] = sqrtf(s2);
        }
    }
}

// ---------------------------------------------------------------------------
// K6: out = feats @ Wout + bout  (unchanged)
// ---------------------------------------------------------------------------
#define KT 16
__global__ __launch_bounds__(256) void k_outproj(
    const float* __restrict__ feats,
    const float* __restrict__ Wout,
    const float* __restrict__ bout,
    float* __restrict__ out)
{
    __shared__ float As[KT][64];   // As[k][row]
    __shared__ float Bs[KT][64];   // Bs[k][col]
    const int t  = threadIdx.x;
    const int n0 = blockIdx.x * 64;
    const int j0 = blockIdx.y * 64;
    const int k0 = blockIdx.z * HSEG;

    const int arow = t >> 2, akq = (t & 3) * 4;
    const int bkk  = t >> 4, bjq = (t & 15) * 4;
    const int tr   = t >> 4, tc  = t & 15;

    float acc[4][4] = {{0.f}};
    for (int s = 0; s < 11; ++s) {
        const int ks = k0 + s * KT;
        float4 a4 = *(const float4*)&feats[(size_t)(n0 + arow) * FEAT_DIM + ks + akq];
        float4 b4 = *(const float4*)&Wout[(size_t)(ks + bkk) * 384 + j0 + bjq];
        __syncthreads();
        As[akq + 0][arow] = a4.x;
        As[akq + 1][arow] = a4.y;
        As[akq + 2][arow] = a4.z;
        As[akq + 3][arow] = a4.w;
        *(float4*)&Bs[bkk][bjq] = b4;
        __syncthreads();
#pragma unroll
        for (int kk = 0; kk < KT; ++kk) {
            float4 av = *(const float4*)&As[kk][tr * 4];
            float4 bv = *(const float4*)&Bs[kk][tc * 4];
            acc[0][0] += av.x * bv.x; acc[0][1] += av.x * bv.y;
            acc[0][2] += av.x * bv.z; acc[0][3] += av.x * bv.w;
            acc[1][0] += av.y * bv.x; acc[1][1] += av.y * bv.y;
            acc[1][2] += av.y * bv.z; acc[1][3] += av.y * bv.w;
            acc[2][0] += av.z * bv.x; acc[2][1] += av.z * bv.y;
            acc[2][2] += av.z * bv.z; acc[2][3] += av.z * bv.w;
            acc[3][0] += av.w * bv.x; acc[3][1] += av.w * bv.y;
            acc[3][2] += av.w * bv.z; acc[3][3] += av.w * bv.w;
        }
    }

    const bool addb = (blockIdx.z == 0);
#pragma unroll
    for (int i = 0; i < 4; ++i) {
        const int row = n0 + tr * 4 + i;
#pragma unroll
        for (int jj = 0; jj < 4; ++jj) {
            const int col = j0 + tc * 4 + jj;
            float v = acc[i][jj];
            if (addb) v += bout[col];
            atomicAdd(&out[(size_t)row * 384 + col], v);
        }
    }
}

// ---------------------------------------------------------------------------
extern "C" void kernel_launch(void* const* d_in, const int* in_sizes, int n_in,
                              void* d_out, int out_size, void* d_ws, size_t ws_size,
                              hipStream_t stream) {
    const float* s     = (const float*)d_in[0];
    const float* z     = (const float*)d_in[1];
    const float* trans = (const float*)d_in[2];
    const float* rot   = (const float*)d_in[3];
    const float* Wq    = (const float*)d_in[4];
    const float* bq    = (const float*)d_in[5];
    const float* Wk    = (const float*)d_in[6];
    const float* bk    = (const float*)d_in[7];
    const float* Wv    = (const float*)d_in[8];
    const float* bv    = (const float*)d_in[9];
    const float* Wqp   = (const float*)d_in[10];
    const float* bqp   = (const float*)d_in[11];
    const float* Wkp   = (const float*)d_in[12];
    const float* bkp   = (const float*)d_in[13];
    const float* Wvp   = (const float*)d_in[14];
    const float* bvp   = (const float*)d_in[15];
    const float* Wb    = (const float*)d_in[16];
    const float* bb    = (const float*)d_in[17];
    const float* emb   = (const float*)d_in[18];
    const float* slog  = (const float*)d_in[19];
    const float* hw    = (const float*)d_in[20];
    const float* Wout  = (const float*)d_in[21];
    const float* bout  = (const float*)d_in[22];

    float* W = (float*)d_ws;
    float* qs     = W;                    // 512*192
    float* ksT    = qs + 98304;           // 192*512 (transposed)
    float* vs     = ksT + 98304;          // 512*192
    float* qg     = vs + 98304;           // 512*144
    float* kgT    = qg + 73728;           // 144*512 (transposed)
    float* vg     = kgT + 73728;          // 512*288
    float* transT = vg + 147456;          // 3*512
    float* attn   = transT + 1536;        // 512*12*512
    float* feats  = attn + 3145728;       // 512*2112
    float* raw_g  = feats + 1081344;      // 512*576
    // total: ~5.11M floats = 20.5 MB

    k_proj<<<dim3(32, 18), 256, 0, stream>>>(s, Wq, bq, Wk, bk, Wv, bv,
                                             Wqp, bqp, Wkp, bkp, Wvp, bvp,
                                             qs, ksT, vs, raw_g);
    k_frame<<<1158, 256, 0, stream>>>(raw_g, trans, rot, qg, kgT, vg, transT);
    k_mid<<<512, 256, 0, stream>>>(z, qs, ksT, qg, kgT, trans, transT,
                                   Wb, bb, emb, slog, hw, attn, feats);
    k_outmm<<<dim3(64, 12), 256, 0, stream>>>(attn, vs, vg, trans, rot, feats);
    hipMemsetAsync(d_out, 0, (size_t)NTOK * 384 * sizeof(float), stream);
    k_outproj<<<dim3(8, 6, 12), 256, 0, stream>>>(feats, Wout, bout, (float*)d_out);
}